// Round 17
// baseline (4142.798 us; speedup 1.0000x reference)
//
#include <hip/hip_runtime.h>

#define TT   1024
#define BB   64
#define DIN  256
#define HH   512
#define DOUT 256

#define NWG_L0  32
#define NWG_L1  64
#define NWG_OUT 4
#define NWG_TOT 100

typedef short bf16x8 __attribute__((ext_vector_type(8)));
typedef float f32x4  __attribute__((ext_vector_type(4)));
typedef unsigned u32x4 __attribute__((ext_vector_type(4)));

// frag-ordered bf16 tensors: index f = ((ks*4 + ct)*64 + lane), element e
// value = M[k = ks*32 + (lane>>4)*8 + e][col = ct*16 + (lane&15)]
__device__ bf16x8 g_xf[TT * 2048];     // x packed (static, cached path)
__device__ bf16x8 g_h1f[4][4096];      // h1 ring, 4 slots (coherent-bypass path)
__device__ bf16x8 g_h2f[4][4096];      // h2 ring
__device__ bf16x8 g_h1z[4096];         // t=-1 zeros (never written)
__device__ bf16x8 g_h2z[4096];

// flags: one 64B line per (producer|consumer) WG, monotone V = Q*2048 + t(+1).
//   fp1  [p(2)][ub(16)]  : 0   + p*16+ub    L0 posts h1[t] ready   (Qb+t+1)
//   fp2  [ct(4)][ub(16)] : 32  + ct*16+ub   L1 posts h2[t] ready   (Qb+t+1)
//   fc1L1[ct(4)][ub(16)] : 96  + ct*16+ub   L1 consumed h1[t]      (Qb+t+1)
//   fc1L0[p(2)][ub(16)]  : 160 + p*16+ub    L0 consumed h1[t-1]    (Qb+t)
//   fc2L1[ct(4)][ub(16)] : 192 + ct*16+ub   L1 consumed h2[t-1]    (Qb+t)
//   fc2OUT[ob(4)]        : 256 + ob         OUT consumed h2[t]     (Qb+t+1)
__device__ unsigned g_flg[260 * 16];
__device__ unsigned g_iter;

__device__ __forceinline__ unsigned* FLG(int idx) { return &g_flg[idx * 16]; }

// ---------- explicitly-coherent (IF-level) primitives: bypass L1+L2
__device__ __forceinline__ u32x4 ldg_cv16(const void* p) {
    u32x4 r;
    asm volatile("global_load_dwordx4 %0, %1, off sc0 sc1"
                 : "=&v"(r) : "v"(p) : "memory");
    return r;
}
__device__ __forceinline__ void stg_cv16(void* p, u32x4 v) {
    asm volatile("global_store_dwordx4 %0, %1, off sc0 sc1" :: "v"(p), "v"(v) : "memory");
}
__device__ __forceinline__ void stg_cv_u32(void* p, unsigned v) {
    asm volatile("global_store_dword %0, %1, off sc0 sc1" :: "v"(p), "v"(v) : "memory");
}
__device__ __forceinline__ void wait_vm0(void) {
    asm volatile("s_waitcnt vmcnt(0)" ::: "memory");
}

// ---------- lane-parallel flag wait (UNSIGNED compare; inactive lanes hold ~0)
__device__ __forceinline__ void waitpoll(const unsigned* p, unsigned tgt, int active, int tid) {
    for (;;) {
        unsigned v = 0xFFFFFFFFu;
        if (active)
            asm volatile("global_load_dword %0, %1, off sc0 sc1\n\t"
                         "s_waitcnt vmcnt(0)"
                         : "=&v"(v) : "v"(p) : "memory");
        if (__all(v >= tgt)) break;
        __builtin_amdgcn_s_sleep(1);
    }
    __syncthreads();
}

__device__ __forceinline__ float sigf(float v) { return 1.f / (1.f + __expf(-v)); }
__device__ __forceinline__ float tanh_fast(float v) { return 2.f / (1.f + __expf(-2.f * v)) - 1.f; }

__device__ __forceinline__ short f2bf(float f) {   // RNE float->bf16 bits
    unsigned u = __builtin_bit_cast(unsigned, f);
    unsigned r = (u + 0x7FFFu + ((u >> 16) & 1u)) >> 16;
    return (short)r;
}

__device__ __forceinline__ bf16x8 pack8(float4 v0, float4 v1) {
    bf16x8 r;
    r[0] = f2bf(v0.x); r[1] = f2bf(v0.y); r[2] = f2bf(v0.z); r[3] = f2bf(v0.w);
    r[4] = f2bf(v1.x); r[5] = f2bf(v1.y); r[6] = f2bf(v1.z); r[7] = f2bf(v1.w);
    return r;
}

// ---------------- pre-pass: pack x (fp32 [T][B][DIN]) into frag-ordered bf16
extern "C" __global__ void __launch_bounds__(256)
pack_x(const float* __restrict__ x) {
    const int t = blockIdx.x, tid = threadIdx.x;
    const float* xt = x + (size_t)t * BB * DIN;
    bf16x8* dst = g_xf + (size_t)t * 2048;
    #pragma unroll
    for (int u = 0; u < 8; ++u) {
        const int f = u * 256 + tid;
        const int lane_ = f & 63, ctks = f >> 6;
        const int ct = ctks & 3, ks = ctks >> 2;
        const int b  = ct * 16 + (lane_ & 15);
        const int kb = ks * 32 + (lane_ >> 4) * 8;
        const float4* s = (const float4*)(xt + b * DIN + kb);
        dst[f] = pack8(s[0], s[1]);
    }
}

// ---------------- LSTM layer: WG owns a 32-unit block x NCT quadrants; wave = 8 units.
// L=0: 32 WGs (p,ub), A = x cached, B = h1[t-1]. L=1: 64 WGs (ct,ub), A = h1[t], B = h2[t-1].
template<int L>
__device__ void run_layer(int lwg, int tid,
                          const float* __restrict__ wih, const float* __restrict__ whh,
                          const float* __restrict__ bih, const float* __restrict__ bhh,
                          float* __restrict__ out, unsigned Q, bf16x8* sB, short* sH)
{
    constexpr int NCT  = (L == 0) ? 2 : 1;
    constexpr int KINX = (L == 0) ? DIN : HH;
    constexpr int NKSA = KINX / 32;          // 8 or 16
    constexpr int NKSB = HH / 32;            // 16
    constexpr int NKS  = NKSA + NKSB;        // 24 or 32
    constexpr int NSTA = NKSA * NCT / 4;     // 4
    constexpr int NSTB = NKSB * NCT / 4;     // 8 or 4

    const int lane = tid & 63, lo = lane & 15, hi = lane >> 4;
    const int w      = tid >> 6;
    const int grp    = (L == 0) ? (lwg & 1) : (lwg & 3);     // p or ct
    const int ub     = (L == 0) ? (lwg >> 1) : (lwg >> 2);   // 0..15
    const int ctbase = (L == 0) ? grp * 2 : grp;
    const int jbase  = ub * 32 + w * 8;

    // --- weights: 2 q-frags per ks (8 units/wave), loaded once, cached
    bf16x8 aF[NKS][2];
    #pragma unroll
    for (int ks = 0; ks < NKS; ++ks)
        #pragma unroll
        for (int q = 0; q < 2; ++q) {
            const int grow = (lo & 3) * HH + jbase + q * 4 + (lo >> 2);
            const float* wr = (ks < NKSA)
                ? wih + (size_t)grow * KINX + ks * 32 + hi * 8
                : whh + (size_t)grow * HH + (ks - NKSA) * 32 + hi * 8;
            const float4* p = (const float4*)wr;
            aF[ks][q] = pack8(p[0], p[1]);
        }

    f32x4 biasv[2];
    #pragma unroll
    for (int q = 0; q < 2; ++q)
        #pragma unroll
        for (int r = 0; r < 4; ++r)
            biasv[q][r] = bih[r * HH + jbase + q * 4 + hi] + bhh[r * HH + jbase + q * 4 + hi];

    const unsigned Qb = Q * 2048u;
    float cst[2][NCT];
    #pragma unroll
    for (int q = 0; q < 2; ++q)
        #pragma unroll
        for (int c = 0; c < NCT; ++c) cst[q][c] = 0.f;

    for (int t = 0; t < TT; ++t) {
        // ---- front merged poll: ready(A / L0-recurrent) + back-pressure
        {
            const unsigned* wp = g_flg; unsigned wt = 0; int wa = 0;
            if (L == 0) {
                if (w == 0) { if (lane < 16 && t >= 1) { wp = FLG(0 + grp * 16 + lane);
                                                         wt = Qb + t; wa = 1; } }
                else if (w == 1 && t >= 4) {
                    if (lane < 16)      { wp = FLG(96 + (2 * grp) * 16 + lane);
                                          wt = Qb + t - 3; wa = 1; }
                    else if (lane < 32) { wp = FLG(96 + (2 * grp + 1) * 16 + (lane - 16));
                                          wt = Qb + t - 3; wa = 1; }
                    else if (lane < 48) { wp = FLG(160 + grp * 16 + (lane - 32));
                                          wt = Qb + t - 3; wa = 1; }
                }
            } else {
                if (w == 0) { if (lane < 16) { wp = FLG(0 + (grp >> 1) * 16 + lane);
                                               wt = Qb + t + 1; wa = 1; } }
                else if (w == 1 && t >= 4) {
                    if (lane < 16)      { wp = FLG(192 + grp * 16 + lane);
                                          wt = Qb + t - 3; wa = 1; }
                    else if (lane < 20) { wp = FLG(256 + (lane - 16));
                                          wt = Qb + t - 3; wa = 1; }
                }
            }
            waitpoll(wp, wt, wa, tid);
        }

        const bf16x8* srcA = (L == 0) ? (g_xf + (size_t)t * 2048) : g_h1f[t & 3];
        const bf16x8* srcB = (L == 0) ? ((t == 0) ? g_h1z : g_h1f[(t - 1) & 3])
                                      : ((t == 0) ? g_h2z : g_h2f[(t - 1) & 3]);

        // ---- stage A (rows ri = ks*NCT+c = r*4+w, ri < NKSA*NCT)
        u32x4 stgA[NSTA];
        #pragma unroll
        for (int r = 0; r < NSTA; ++r) {
            const int ri = r * 4 + w, ks = ri / NCT, c = ri % NCT;
            const bf16x8* src = &srcA[(ks * 4 + ctbase + c) * 64 + lane];
            if (L == 0) stgA[r] = *(const u32x4*)src;
            else        stgA[r] = ldg_cv16(src);
        }
        wait_vm0();
        #pragma unroll
        for (int r = 0; r < NSTA; ++r)
            ((u32x4*)sB)[(r * 4 + w) * 64 + lane] = stgA[r];
        __syncthreads();
        if (L == 1 && tid == 0) stg_cv_u32(FLG(96 + grp * 16 + ub), Qb + t + 1);

        // ---- recurrent poll (L1 only; L0's was in the front poll)
        if (L == 1) {
            const unsigned* wp = g_flg; unsigned wt = 0; int wa = 0;
            if (w == 0 && lane < 16 && t >= 1) { wp = FLG(32 + grp * 16 + lane);
                                                 wt = Qb + t; wa = 1; }
            waitpoll(wp, wt, wa, tid);
        }

        // ---- stage B (issue), overlap A-part MFMAs under the load latency
        u32x4 stgB[NSTB];
        #pragma unroll
        for (int r = 0; r < NSTB; ++r) {
            const int ri = r * 4 + w, ks = ri / NCT, c = ri % NCT;
            stgB[r] = ldg_cv16(&srcB[(ks * 4 + ctbase + c) * 64 + lane]);
        }
        f32x4 acc[2][NCT];
        #pragma unroll
        for (int q = 0; q < 2; ++q)
            #pragma unroll
            for (int c = 0; c < NCT; ++c) acc[q][c] = biasv[q];
        #pragma unroll
        for (int ks = 0; ks < NKSA; ++ks)
            #pragma unroll
            for (int q = 0; q < 2; ++q)
                #pragma unroll
                for (int c = 0; c < NCT; ++c)
                    acc[q][c] = __builtin_amdgcn_mfma_f32_16x16x32_bf16(
                        aF[ks][q], sB[(ks * NCT + c) * 64 + lane], acc[q][c], 0, 0, 0);
        wait_vm0();
        #pragma unroll
        for (int r = 0; r < NSTB; ++r)
            ((u32x4*)sB)[(NKSA * NCT + r * 4 + w) * 64 + lane] = stgB[r];
        __syncthreads();
        if (tid == 0) {
            if (L == 0) stg_cv_u32(FLG(160 + grp * 16 + ub), Qb + t);
            else        stg_cv_u32(FLG(192 + grp * 16 + ub), Qb + t);
        }
        #pragma unroll
        for (int ks = NKSA; ks < NKS; ++ks)
            #pragma unroll
            for (int q = 0; q < 2; ++q)
                #pragma unroll
                for (int c = 0; c < NCT; ++c)
                    acc[q][c] = __builtin_amdgcn_mfma_f32_16x16x32_bf16(
                        aF[ks][q], sB[(ks * NCT + c) * 64 + lane], acc[q][c], 0, 0, 0);

        // ---- activation; pack into sH: unit u = w*8+q*4+hi -> sH[(c*64 + w*16+lo)*8 + q*4+hi]
        #pragma unroll
        for (int q = 0; q < 2; ++q)
            #pragma unroll
            for (int c = 0; c < NCT; ++c) {
                const float gi = acc[q][c][0], gf = acc[q][c][1];
                const float gg = acc[q][c][2], go = acc[q][c][3];
                const float cn_ = sigf(gf) * cst[q][c] + sigf(gi) * tanh_fast(gg);
                const float hv  = sigf(go) * tanh_fast(cn_);
                cst[q][c] = cn_;
                sH[((c * 64) + w * 16 + lo) * 8 + q * 4 + hi] = f2bf(hv);
                if (t == TT - 1) {
                    const int j = jbase + q * 4 + hi, b = (ctbase + c) * 16 + lo;
                    const size_t base = (size_t)TT * BB * DOUT;
                    out[base + (size_t)L * BB * HH + (size_t)b * HH + j] = hv;
                    out[base + (size_t)2 * BB * HH + (size_t)L * BB * HH + (size_t)b * HH + j] = cn_;
                }
            }
        __syncthreads();   // publish sH

        // ---- ring write: WG's 32-unit block = ONE full frag-row per quadrant
        u32x4* ringW = (u32x4*)((L == 0) ? g_h1f[t & 3] : g_h2f[t & 3]);
        if (tid < 64 * NCT) {
            const int c = tid >> 6, l = tid & 63;
            stg_cv16(ringW + (ub * 4 + ctbase + c) * 64 + l,
                     *(const u32x4*)&sH[(c * 64 + l) * 8]);
        }
        wait_vm0();
        __syncthreads();   // all storing waves drained before the post
        if (tid == 0) {
            if (L == 0) stg_cv_u32(FLG(0 + grp * 16 + ub), Qb + t + 1);
            else        stg_cv_u32(FLG(32 + grp * 16 + ub), Qb + t + 1);
        }
    }
}

// ---------------- output projection: 4 WGs, each 64 odims x full batch; wave = 16 odims
__device__ void run_out(int ob, int tid,
                        const float* __restrict__ wout, const float* __restrict__ bout,
                        float* __restrict__ out, unsigned Q, bf16x8* sB)
{
    constexpr int NKS = HH / 32;   // 16
    constexpr int NST = 16;        // 64 rows / 4 waves
    const int lane = tid & 63, lo = lane & 15, hi = lane >> 4;
    const int w = tid >> 6;
    const int ow = ob * 64 + w * 16;
    const unsigned Qb = Q * 2048u;

    bf16x8 aF[NKS];
    #pragma unroll
    for (int ks = 0; ks < NKS; ++ks) {
        const float4* p = (const float4*)(wout + (size_t)(ow + lo) * HH + ks * 32 + hi * 8);
        aF[ks] = pack8(p[0], p[1]);
    }
    f32x4 biasv;
    #pragma unroll
    for (int r = 0; r < 4; ++r) biasv[r] = bout[ow + hi * 4 + r];

    for (int t = 0; t < TT; ++t) {
        {   // h2[t] ready: all 64 L1 producer flags, one per lane
            const unsigned* wp = g_flg; unsigned wt = 0; int wa = 0;
            if (w == 0) { wp = FLG(32 + (lane >> 4) * 16 + (lane & 15));
                          wt = Qb + t + 1; wa = 1; }
            waitpoll(wp, wt, wa, tid);
        }
        const bf16x8* src = g_h2f[t & 3];
        u32x4 stg[NST];
        #pragma unroll
        for (int r = 0; r < NST; ++r) {
            const int ri = r * 4 + w;     // = ks*4 + c
            stg[r] = ldg_cv16(&src[ri * 64 + lane]);
        }
        wait_vm0();
        #pragma unroll
        for (int r = 0; r < NST; ++r)
            ((u32x4*)sB)[(r * 4 + w) * 64 + lane] = stg[r];
        __syncthreads();
        if (tid == 0) stg_cv_u32(FLG(256 + ob), Qb + t + 1);

        f32x4 acc[4] = {biasv, biasv, biasv, biasv};
        #pragma unroll
        for (int ks = 0; ks < NKS; ++ks)
            #pragma unroll
            for (int c = 0; c < 4; ++c)
                acc[c] = __builtin_amdgcn_mfma_f32_16x16x32_bf16(
                    aF[ks], sB[(ks * 4 + c) * 64 + lane], acc[c], 0, 0, 0);
        #pragma unroll
        for (int c = 0; c < 4; ++c)
            #pragma unroll
            for (int r = 0; r < 4; ++r) {
                const int b = c * 16 + lo, o = ow + hi * 4 + r;
                out[(size_t)t * BB * DOUT + (size_t)b * DOUT + o] = acc[c][r];
            }
    }
}

extern "C" __global__ void __launch_bounds__(256, 1)
lstm2_fused(const float* __restrict__ x,
            const float* __restrict__ wih0, const float* __restrict__ whh0,
            const float* __restrict__ bih0, const float* __restrict__ bhh0,
            const float* __restrict__ wih1, const float* __restrict__ whh1,
            const float* __restrict__ bih1, const float* __restrict__ bhh1,
            const float* __restrict__ wout, const float* __restrict__ bout,
            float* __restrict__ out)
{
    __shared__ bf16x8 sB[4096];                     // 64KB: OUT uses all; L0 48KB; L1 32KB
    __shared__ __align__(16) short sH[2 * 64 * 8];  // 2KB h-pack (NCT quadrants x 1KB)

    const int tid = threadIdx.x, wg = blockIdx.x;
    const unsigned Q = __hip_atomic_load(&g_iter, __ATOMIC_RELAXED, __HIP_MEMORY_SCOPE_AGENT);

    if (wg < NWG_L0)
        run_layer<0>(wg, tid, wih0, whh0, bih0, bhh0, out, Q, sB, sH);
    else if (wg < NWG_L0 + NWG_L1)
        run_layer<1>(wg - NWG_L0, tid, wih1, whh1, bih1, bhh1, out, Q, sB, sH);
    else
        run_out(wg - NWG_L0 - NWG_L1, tid, wout, bout, out, Q, sB);

    // wg0 (an L0 WG) exits only after the pipeline drained; every WG read Q long ago.
    if (wg == 0 && tid == 0)
        __hip_atomic_store(&g_iter, Q + 1, __ATOMIC_RELAXED, __HIP_MEMORY_SCOPE_AGENT);
}

extern "C" void kernel_launch(void* const* d_in, const int* in_sizes, int n_in,
                              void* d_out, int out_size, void* d_ws, size_t ws_size,
                              hipStream_t stream) {
    const float* x    = (const float*)d_in[0];
    const float* wih0 = (const float*)d_in[1];
    const float* whh0 = (const float*)d_in[2];
    const float* bih0 = (const float*)d_in[3];
    const float* bhh0 = (const float*)d_in[4];
    const float* wih1 = (const float*)d_in[5];
    const float* whh1 = (const float*)d_in[6];
    const float* bih1 = (const float*)d_in[7];
    const float* bhh1 = (const float*)d_in[8];
    const float* wout = (const float*)d_in[9];
    const float* bout = (const float*)d_in[10];
    float* out = (float*)d_out;

    hipLaunchKernelGGL(pack_x, dim3(TT), dim3(256), 0, stream, x);
    hipLaunchKernelGGL(lstm2_fused, dim3(NWG_TOT), dim3(256), 0, stream,
                       x, wih0, whh0, bih0, bhh0, wih1, whh1, bih1, bhh1,
                       wout, bout, out);
}

// Round 18
// 3729.634 us; speedup vs baseline: 1.1108x; 1.1108x over previous
//
#include <hip/hip_runtime.h>

#define TT   1024
#define BB   64
#define DIN  256
#define HH   512
#define DOUT 256

#define NWG_L0  64
#define NWG_L1  128
#define NWG_OUT 8
#define NWG_TOT 200

typedef short bf16x8 __attribute__((ext_vector_type(8)));
typedef float f32x4  __attribute__((ext_vector_type(4)));
typedef unsigned u32x4 __attribute__((ext_vector_type(4)));

// frag-ordered bf16 tensors: index f = ((ks*4 + ct)*64 + lane), element e
// value = M[k = ks*32 + (lane>>4)*8 + e][col = ct*16 + (lane&15)]
__device__ bf16x8 g_xf[TT * 2048];     // x packed (static, cached path)
__device__ bf16x8 g_h1f[8][4096];      // h1 ring, 8 slots (coherent-bypass path)
__device__ bf16x8 g_h2f[8][4096];      // h2 ring, 8 slots
__device__ bf16x8 g_h1z[4096];         // t=-1 zeros (never written)
__device__ bf16x8 g_h2z[4096];

// per-WG progress flags, one 64B line each, monotone V = Q*2048 + t(+1). R14/R15 layout:
//   fp1  [p(2)][ub(32)]   : 0   + p*32+ub    L0 posts h1[t] ready    (Qb+t+1)
//   fp2  [ct(4)][ub2(32)] : 64  + ct*32+ub2  L1 posts h2[t] ready    (Qb+t+1)
//   fc1L1[ct(4)][ub2(32)] : 192 + ct*32+ub2  L1 consumed h1[t]       (Qb+t+1)
//   fc1L0[p(2)][ub(32)]   : 320 + p*32+ub    L0 consumed h1[t-1]     (Qb+t)
//   fc2L1[ct(4)][ub2(32)] : 384 + ct*32+ub2  L1 consumed h2[t-1]     (Qb+t)
//   fc2OUT[cp(2)*4+ob(4)] : 512 + cp*4+ob    OUT consumed h2[t]      (Qb+t+1)
// 8-deep rings: BP checked only at t%4==0 (front, L0) / t%4==3 (tail, L1), t>=8,
// uniform target Qb+t-4 (covers the next 4 slot writes; desk-checked all classes).
__device__ unsigned g_flg[520 * 16];
__device__ unsigned g_iter;

__device__ __forceinline__ unsigned* FLG(int idx) { return &g_flg[idx * 16]; }

// ---------- explicitly-coherent (IF-level) primitives: bypass L1+L2
__device__ __forceinline__ u32x4 ldg_cv16(const void* p) {
    u32x4 r;
    asm volatile("global_load_dwordx4 %0, %1, off sc0 sc1"
                 : "=&v"(r) : "v"(p) : "memory");
    return r;
}
__device__ __forceinline__ void stg_cv16(void* p, u32x4 v) {
    asm volatile("global_store_dwordx4 %0, %1, off sc0 sc1" :: "v"(p), "v"(v) : "memory");
}
__device__ __forceinline__ void stg_cv_u32(void* p, unsigned v) {
    asm volatile("global_store_dword %0, %1, off sc0 sc1" :: "v"(p), "v"(v) : "memory");
}
__device__ __forceinline__ void wait_vm0(void) {
    asm volatile("s_waitcnt vmcnt(0)" ::: "memory");
}

// ---------- lane-parallel flag wait (UNSIGNED compare; inactive lanes hold ~0)
__device__ __forceinline__ void waitpoll(const unsigned* p, unsigned tgt, int active, int tid) {
    for (;;) {
        unsigned v = 0xFFFFFFFFu;
        if (active)
            asm volatile("global_load_dword %0, %1, off sc0 sc1\n\t"
                         "s_waitcnt vmcnt(0)"
                         : "=&v"(v) : "v"(p) : "memory");
        if (__all(v >= tgt)) break;
        __builtin_amdgcn_s_sleep(1);
    }
    __syncthreads();
}

__device__ __forceinline__ float sigf(float v) { return 1.f / (1.f + __expf(-v)); }
__device__ __forceinline__ float tanh_fast(float v) { return 2.f / (1.f + __expf(-2.f * v)) - 1.f; }

__device__ __forceinline__ short f2bf(float f) {   // RNE float->bf16 bits
    unsigned u = __builtin_bit_cast(unsigned, f);
    unsigned r = (u + 0x7FFFu + ((u >> 16) & 1u)) >> 16;
    return (short)r;
}

__device__ __forceinline__ bf16x8 pack8(float4 v0, float4 v1) {
    bf16x8 r;
    r[0] = f2bf(v0.x); r[1] = f2bf(v0.y); r[2] = f2bf(v0.z); r[3] = f2bf(v0.w);
    r[4] = f2bf(v1.x); r[5] = f2bf(v1.y); r[6] = f2bf(v1.z); r[7] = f2bf(v1.w);
    return r;
}

// ---------------- pre-pass: pack x (fp32 [T][B][DIN]) into frag-ordered bf16
extern "C" __global__ void __launch_bounds__(256)
pack_x(const float* __restrict__ x) {
    const int t = blockIdx.x, tid = threadIdx.x;
    const float* xt = x + (size_t)t * BB * DIN;
    bf16x8* dst = g_xf + (size_t)t * 2048;
    #pragma unroll
    for (int u = 0; u < 8; ++u) {
        const int f = u * 256 + tid;
        const int lane_ = f & 63, ctks = f >> 6;
        const int ct = ctks & 3, ks = ctks >> 2;
        const int b  = ct * 16 + (lane_ & 15);
        const int kb = ks * 32 + (lane_ >> 4) * 8;
        const float4* s = (const float4*)(xt + b * DIN + kb);
        dst[f] = pack8(s[0], s[1]);
    }
}

// ---------------- L0: 64 WGs (ub 0..31 x p 0..1), wave = 4 units, NCT=2 quadrants.
// ONE merged front poll (recurrent h1[t-1] + amortized BP), merged A+B staging.
__device__ void run_l0(int lwg, int tid,
                       const float* __restrict__ wih, const float* __restrict__ whh,
                       const float* __restrict__ bih, const float* __restrict__ bhh,
                       float* __restrict__ out, unsigned Q, bf16x8* sB, short* sH)
{
    constexpr int NCT = 2, NKSA = DIN / 32, NKS = NKSA + HH / 32;   // 8, 24
    constexpr int NST = NKS * NCT / 4;                               // 12
    constexpr int NCXR = NKSA * NCT / 4;                             // 4 cached rounds

    const int lane = tid & 63, lo = lane & 15, hi = lane >> 4;
    const int w = tid >> 6;
    const int grp = lwg & 1, ub = lwg >> 1;
    const int ctbase = grp * 2;
    const int wv = ub * 4 + w, jbase = wv * 4;
    const int grow = (lo & 3) * HH + jbase + (lo >> 2);

    bf16x8 aF[NKS];
    #pragma unroll
    for (int ks = 0; ks < NKS; ++ks) {
        const float* wr = (ks < NKSA) ? wih + (size_t)grow * DIN + ks * 32 + hi * 8
                                      : whh + (size_t)grow * HH + (ks - NKSA) * 32 + hi * 8;
        const float4* p = (const float4*)wr;
        aF[ks] = pack8(p[0], p[1]);
    }
    f32x4 biasv;
    #pragma unroll
    for (int r = 0; r < 4; ++r)
        biasv[r] = bih[r * HH + jbase + hi] + bhh[r * HH + jbase + hi];

    const unsigned Qb = Q * 2048u;
    float cst[NCT] = {0.f, 0.f};

    for (int t = 0; t < TT; ++t) {
        // ---- ONE front poll: h1[t-1] ready (w0) + BP every 4th step (w1/w2)
        {
            const unsigned* wp = g_flg; unsigned wt = 0; int wa = 0;
            const int bp = (t >= 8) && ((t & 3) == 0);
            if (w == 0) { if (lane < 32 && t >= 1) { wp = FLG(0 + grp * 32 + lane);
                                                     wt = Qb + t; wa = 1; } }
            else if (w == 1) { if (bp) {
                wp = FLG(192 + (grp * 2 + (lane >> 5)) * 32 + (lane & 31));
                wt = Qb + t - 4; wa = 1; } }
            else if (w == 2) { if (bp && lane < 32) {
                wp = FLG(320 + grp * 32 + lane); wt = Qb + t - 4; wa = 1; } }
            waitpoll(wp, wt, wa, tid);   // syncthreads = sB/sH reuse fence
        }

        const bf16x8* srcA = g_xf + (size_t)t * 2048;
        const bf16x8* srcB = (t == 0) ? g_h1z : g_h1f[(t - 1) & 7];

        // ---- stage A (cached x) + B (bypass h1) in one batch
        u32x4 stg[NST];
        #pragma unroll
        for (int r = 0; r < NST; ++r) {
            const int ri = r * 4 + w, ks = ri / NCT, c = ri % NCT;
            if (r < NCXR) stg[r] = *(const u32x4*)&srcA[(ks * 4 + ctbase + c) * 64 + lane];
            else          stg[r] = ldg_cv16(&srcB[((ks - NKSA) * 4 + ctbase + c) * 64 + lane]);
        }
        wait_vm0();
        #pragma unroll
        for (int r = 0; r < NST; ++r)
            ((u32x4*)sB)[(r * 4 + w) * 64 + lane] = stg[r];
        __syncthreads();
        if (tid == 0) stg_cv_u32(FLG(320 + grp * 32 + ub), Qb + t);   // consumed h1[t-1]

        f32x4 acc[NCT] = {biasv, biasv};
        #pragma unroll
        for (int ks = 0; ks < NKS; ++ks)
            #pragma unroll
            for (int c = 0; c < NCT; ++c)
                acc[c] = __builtin_amdgcn_mfma_f32_16x16x32_bf16(
                    aF[ks], sB[(ks * NCT + c) * 64 + lane], acc[c], 0, 0, 0);

        #pragma unroll
        for (int c = 0; c < NCT; ++c) {
            const float gi = acc[c][0], gf = acc[c][1];
            const float gg = acc[c][2], go = acc[c][3];
            const float cn_ = sigf(gf) * cst[c] + sigf(gi) * tanh_fast(gg);
            const float hv  = sigf(go) * tanh_fast(cn_);
            cst[c] = cn_;
            sH[((c * 2 + (w >> 1)) * 16 + lo) * 8 + (w & 1) * 4 + hi] = f2bf(hv);
            if (t == TT - 1) {
                const int j = jbase + hi, b = (ctbase + c) * 16 + lo;
                const size_t base = (size_t)TT * BB * DOUT;
                out[base + (size_t)b * HH + j] = hv;
                out[base + (size_t)2 * BB * HH + (size_t)b * HH + j] = cn_;
            }
        }
        __syncthreads();   // publish sH to wave0

        u32x4* ringW = (u32x4*)g_h1f[t & 7];
        if (tid < 64) {   // wave0: 64 x 16B coherent stores (2 quadrants)
            const int c = tid >> 5, r = tid & 31, hi2 = r >> 4, lo2 = r & 15;
            const int f = ((ub >> 1) * 4 + ctbase + c) * 64 + ((ub & 1) * 2 + hi2) * 16 + lo2;
            stg_cv16(ringW + f, *(const u32x4*)&sH[((c * 2 + hi2) * 16 + lo2) * 8]);
        }
        wait_vm0();
        if (tid == 0) stg_cv_u32(FLG(0 + grp * 32 + ub), Qb + t + 1);
    }
}

// ---------------- L1: 128 WGs (ub2 0..31 x ct 0..3), wave = 4 units, NCT=1.
// Split-phase: stage A(h1[t]) -> critical h2 poll -> B-loads || A-MFMAs. Tail poll
// (pre-satisfied) checks h1[t+1] + amortized BP and doubles as the reuse fence.
__device__ void run_l1(int lwg, int tid,
                       const float* __restrict__ wih, const float* __restrict__ whh,
                       const float* __restrict__ bih, const float* __restrict__ bhh,
                       float* __restrict__ out, unsigned Q, bf16x8* sB, short* sH)
{
    constexpr int NKSA = HH / 32, NKS = 2 * NKSA;   // 16, 32
    constexpr int NSTA = NKSA / 4, NSTB = NKSA / 4; // 4, 4

    const int lane = tid & 63, lo = lane & 15, hi = lane >> 4;
    const int w = tid >> 6;
    const int grp = lwg & 3, ub = lwg >> 2;       // ct, ub2
    const int ctbase = grp;
    const int wv = ub * 4 + w, jbase = wv * 4;
    const int grow = (lo & 3) * HH + jbase + (lo >> 2);

    bf16x8 aF[NKS];
    #pragma unroll
    for (int ks = 0; ks < NKS; ++ks) {
        const float* wr = (ks < NKSA) ? wih + (size_t)grow * HH + ks * 32 + hi * 8
                                      : whh + (size_t)grow * HH + (ks - NKSA) * 32 + hi * 8;
        const float4* p = (const float4*)wr;
        aF[ks] = pack8(p[0], p[1]);
    }
    f32x4 biasv;
    #pragma unroll
    for (int r = 0; r < 4; ++r)
        biasv[r] = bih[r * HH + jbase + hi] + bhh[r * HH + jbase + hi];

    const unsigned Qb = Q * 2048u;
    float cst = 0.f;

    // prologue: h1[0] ready
    {
        const unsigned* wp = g_flg; unsigned wt = 0; int wa = 0;
        if (w == 0 && lane < 32) { wp = FLG(0 + (grp >> 1) * 32 + lane); wt = Qb + 1; wa = 1; }
        waitpoll(wp, wt, wa, tid);
    }

    for (int t = 0; t < TT; ++t) {
        const bf16x8* srcA = g_h1f[t & 7];
        const bf16x8* srcB = (t == 0) ? g_h2z : g_h2f[(t - 1) & 7];

        // ---- stage A = h1[t] (readiness from previous tail poll / prologue)
        u32x4 stgA[NSTA];
        #pragma unroll
        for (int r = 0; r < NSTA; ++r) {
            const int ks = r * 4 + w;
            stgA[r] = ldg_cv16(&srcA[(ks * 4 + ctbase) * 64 + lane]);
        }
        wait_vm0();
        #pragma unroll
        for (int r = 0; r < NSTA; ++r)
            ((u32x4*)sB)[(r * 4 + w) * 64 + lane] = stgA[r];
        __syncthreads();
        if (tid == 0) stg_cv_u32(FLG(192 + grp * 32 + ub), Qb + t + 1);  // consumed h1[t]

        // ---- critical poll: h2[t-1] ready
        {
            const unsigned* wp = g_flg; unsigned wt = 0; int wa = 0;
            if (w == 0 && lane < 32 && t >= 1) { wp = FLG(64 + grp * 32 + lane);
                                                 wt = Qb + t; wa = 1; }
            waitpoll(wp, wt, wa, tid);
        }

        // ---- B loads || A-MFMAs
        u32x4 stgB[NSTB];
        #pragma unroll
        for (int r = 0; r < NSTB; ++r) {
            const int ks = r * 4 + w;
            stgB[r] = ldg_cv16(&srcB[(ks * 4 + ctbase) * 64 + lane]);
        }
        f32x4 acc = biasv;
        #pragma unroll
        for (int ks = 0; ks < NKSA; ++ks)
            acc = __builtin_amdgcn_mfma_f32_16x16x32_bf16(
                aF[ks], sB[ks * 64 + lane], acc, 0, 0, 0);
        wait_vm0();
        #pragma unroll
        for (int r = 0; r < NSTB; ++r)
            ((u32x4*)sB)[(NKSA + r * 4 + w) * 64 + lane] = stgB[r];
        __syncthreads();
        if (tid == 0) stg_cv_u32(FLG(384 + grp * 32 + ub), Qb + t);   // consumed h2[t-1]
        #pragma unroll
        for (int ks = NKSA; ks < NKS; ++ks)
            acc = __builtin_amdgcn_mfma_f32_16x16x32_bf16(
                aF[ks], sB[ks * 64 + lane], acc, 0, 0, 0);

        // ---- activation + sH pack
        {
            const float gi = acc[0], gf = acc[1], gg = acc[2], go = acc[3];
            const float cn_ = sigf(gf) * cst + sigf(gi) * tanh_fast(gg);
            const float hv  = sigf(go) * tanh_fast(cn_);
            cst = cn_;
            sH[((w >> 1) * 16 + lo) * 8 + (w & 1) * 4 + hi] = f2bf(hv);
            if (t == TT - 1) {
                const int j = jbase + hi, b = ctbase * 16 + lo;
                const size_t base = (size_t)TT * BB * DOUT;
                out[base + (size_t)BB * HH + (size_t)b * HH + j] = hv;
                out[base + (size_t)3 * BB * HH + (size_t)b * HH + j] = cn_;
            }
        }
        __syncthreads();

        u32x4* ringW = (u32x4*)g_h2f[t & 7];
        if (tid < 32) {
            const int hi2 = tid >> 4, lo2 = tid & 15;
            const int f = ((ub >> 1) * 4 + ctbase) * 64 + ((ub & 1) * 2 + hi2) * 16 + lo2;
            stg_cv16(ringW + f, *(const u32x4*)&sH[(hi2 * 16 + lo2) * 8]);
        }
        wait_vm0();
        if (tid == 0) stg_cv_u32(FLG(64 + grp * 32 + ub), Qb + t + 1);

        // ---- tail poll: h1[t+1] ready (pre-satisfied) + BP when t%4==3, t>=7
        if (t < TT - 1) {
            const unsigned* wp = g_flg; unsigned wt = 0; int wa = 0;
            const int bp = (t >= 7) && ((t & 3) == 3);
            if (w == 0) { if (lane < 32) { wp = FLG(0 + (grp >> 1) * 32 + lane);
                                           wt = Qb + t + 2; wa = 1; } }
            else if (w == 1) { if (bp) {
                if (lane < 32)      { wp = FLG(384 + grp * 32 + lane);
                                      wt = Qb + t - 3; wa = 1; }
                else if (lane < 36) { wp = FLG(512 + (grp >> 1) * 4 + (lane - 32));
                                      wt = Qb + t - 3; wa = 1; } } }
            waitpoll(wp, wt, wa, tid);   // syncthreads = next-step sB/sH reuse fence
        }
    }
}

// ---------------- output projection: 8 WGs = (ob 0..3, cp 0..1); wave = 16 odims
__device__ void run_out(int lwg, int tid,
                        const float* __restrict__ wout, const float* __restrict__ bout,
                        float* __restrict__ out, unsigned Q, bf16x8* sB)
{
    constexpr int NKS = HH / 32;   // 16
    constexpr int NST = 8;         // 32 staged rows / 4 waves
    const int lane = tid & 63, lo = lane & 15, hi = lane >> 4;
    const int w = tid >> 6;
    const int cp = lwg & 1, ob = lwg >> 1;
    const int ctbase = cp * 2;
    const int obase = (ob * 4 + w) * 16;
    const unsigned Qb = Q * 2048u;

    bf16x8 aF[NKS];
    #pragma unroll
    for (int ks = 0; ks < NKS; ++ks) {
        const float4* p = (const float4*)(wout + (size_t)(obase + lo) * HH + ks * 32 + hi * 8);
        aF[ks] = pack8(p[0], p[1]);
    }
    f32x4 biasv;
    #pragma unroll
    for (int r = 0; r < 4; ++r) biasv[r] = bout[obase + hi * 4 + r];

    for (int t = 0; t < TT; ++t) {
        const unsigned* wp = g_flg; unsigned wt = 0; int wa = 0;
        if (w == 0) {
            wp = FLG(64 + (ctbase + (lane >> 5)) * 32 + (lane & 31));
            wt = Qb + t + 1; wa = 1;
        }
        waitpoll(wp, wt, wa, tid);

        const bf16x8* src = g_h2f[t & 7];
        u32x4 stg[NST];
        #pragma unroll
        for (int r = 0; r < NST; ++r) {
            const int ri = r * 4 + w;
            const int ks = ri >> 1, c = ri & 1;
            stg[r] = ldg_cv16(&src[(ks * 4 + ctbase + c) * 64 + lane]);
        }
        wait_vm0();
        #pragma unroll
        for (int r = 0; r < NST; ++r)
            ((u32x4*)sB)[(r * 4 + w) * 64 + lane] = stg[r];
        __syncthreads();
        if (tid == 0) stg_cv_u32(FLG(512 + cp * 4 + ob), Qb + t + 1);

        f32x4 acc[2] = {biasv, biasv};
        #pragma unroll
        for (int ks = 0; ks < NKS; ++ks)
            #pragma unroll
            for (int c = 0; c < 2; ++c)
                acc[c] = __builtin_amdgcn_mfma_f32_16x16x32_bf16(
                    aF[ks], sB[(ks * 2 + c) * 64 + lane], acc[c], 0, 0, 0);
        #pragma unroll
        for (int c = 0; c < 2; ++c)
            #pragma unroll
            for (int r = 0; r < 4; ++r) {
                const int b = (ctbase + c) * 16 + lo, o = obase + hi * 4 + r;
                out[(size_t)t * BB * DOUT + (size_t)b * DOUT + o] = acc[c][r];
            }
    }
}

extern "C" __global__ void __launch_bounds__(256, 1)
lstm2_fused(const float* __restrict__ x,
            const float* __restrict__ wih0, const float* __restrict__ whh0,
            const float* __restrict__ bih0, const float* __restrict__ bhh0,
            const float* __restrict__ wih1, const float* __restrict__ whh1,
            const float* __restrict__ bih1, const float* __restrict__ bhh1,
            const float* __restrict__ wout, const float* __restrict__ bout,
            float* __restrict__ out)
{
    __shared__ bf16x8 sB[3072];                         // 48KB staging
    __shared__ __align__(16) short sH[2 * 2 * 16 * 8];  // 1KB h-pack buffer

    const int tid = threadIdx.x, wg = blockIdx.x;
    const unsigned Q = __hip_atomic_load(&g_iter, __ATOMIC_RELAXED, __HIP_MEMORY_SCOPE_AGENT);

    if (wg < NWG_L0)
        run_l0(wg, tid, wih0, whh0, bih0, bhh0, out, Q, sB, sH);
    else if (wg < NWG_L0 + NWG_L1)
        run_l1(wg - NWG_L0, tid, wih1, whh1, bih1, bhh1, out, Q, sB, sH);
    else
        run_out(wg - NWG_L0 - NWG_L1, tid, wout, bout, out, Q, sB);

    if (wg == 0 && tid == 0)
        __hip_atomic_store(&g_iter, Q + 1, __ATOMIC_RELAXED, __HIP_MEMORY_SCOPE_AGENT);
}

extern "C" void kernel_launch(void* const* d_in, const int* in_sizes, int n_in,
                              void* d_out, int out_size, void* d_ws, size_t ws_size,
                              hipStream_t stream) {
    const float* x    = (const float*)d_in[0];
    const float* wih0 = (const float*)d_in[1];
    const float* whh0 = (const float*)d_in[2];
    const float* bih0 = (const float*)d_in[3];
    const float* bhh0 = (const float*)d_in[4];
    const float* wih1 = (const float*)d_in[5];
    const float* whh1 = (const float*)d_in[6];
    const float* bih1 = (const float*)d_in[7];
    const float* bhh1 = (const float*)d_in[8];
    const float* wout = (const float*)d_in[9];
    const float* bout = (const float*)d_in[10];
    float* out = (float*)d_out;

    hipLaunchKernelGGL(pack_x, dim3(TT), dim3(256), 0, stream, x);
    hipLaunchKernelGGL(lstm2_fused, dim3(NWG_TOT), dim3(256), 0, stream,
                       x, wih0, whh0, bih0, bhh0, wih1, whh1, bih1, bhh1,
                       wout, bout, out);
}